// Round 9
// baseline (177.997 us; speedup 1.0000x reference)
//
#include <hip/hip_runtime.h>
#include <math.h>

#define N_NODES 4096
#define DIM 256
#define NH 4
#define NG 16
#define LN_EPS 1e-5f
#define TEMP 5.0f
#define RSLACK 4160     // 4096 + 64 rows of slack for attention tile-tail reads
#define PS_STRIDE 72    // bf16 elems; 144 B row stride, 2-way aliasing only (free)
#define BS_STRIDE 264   // bf16 elems; 528 B row stride -> 2-way-free b128 reads
#define QT_MAX 24       // 24*16 = 384 max rows/graph
#define ATTN_BLOCKS (NG * QT_MAX)  // 384: block=(g,qt16), wave=head

typedef __attribute__((ext_vector_type(8))) short short8;
typedef __attribute__((ext_vector_type(4))) short short4_t;
typedef __attribute__((ext_vector_type(4))) float f32x4;

__device__ __forceinline__ unsigned short f2bf(float f) {
    unsigned u = __builtin_bit_cast(unsigned, f);
    u += 0x7FFFu + ((u >> 16) & 1u);  // RNE
    return (unsigned short)(u >> 16);
}
__device__ __forceinline__ float bf2f(unsigned short u) {
    return __builtin_bit_cast(float, (unsigned)u << 16);
}
__device__ __forceinline__ float fsigmoid(float z) { return 1.f / (1.f + __expf(-z)); }
__device__ __forceinline__ float ftanh(float z) {
    float t = __expf(2.f * z);
    return (t - 1.f) / (t + 1.f);
}
__device__ __forceinline__ int seg_search(const int* __restrict__ batch, int g) {
    int lo = 0, hi = N_NODES;
    while (lo < hi) {
        int mid = (lo + hi) >> 1;
        if (batch[mid] < g) lo = mid + 1; else hi = mid;
    }
    return lo;
}

// A-fragment: 8 consecutive k of f32 x, cast bf16 in-register (same RNE values
// as a staged bf16 copy of x -> numerics identical, no prep kernel).
__device__ __forceinline__ short8 afrag_f32(const float* __restrict__ x, int row, int k0) {
    float4 a = *(const float4*)&x[(size_t)row * 256 + k0];
    float4 b = *(const float4*)&x[(size_t)row * 256 + k0 + 4];
    short8 r = {(short)f2bf(a.x), (short)f2bf(a.y), (short)f2bf(a.z), (short)f2bf(a.w),
                (short)f2bf(b.x), (short)f2bf(b.y), (short)f2bf(b.z), (short)f2bf(b.w)};
    return r;
}

// Cooperative 64-col W-tile load + transpose + bf16 cast into LDS: Bs[c][k].
__device__ __forceinline__ void ldsB(const float* __restrict__ W, int ws, int bn,
                                     unsigned short* __restrict__ Bs) {
    int c4 = (threadIdx.x & 15) * 4;
    int r0 = threadIdx.x >> 4;
    for (int p = 0; p < 16; ++p) {
        int k = p * 16 + r0;
        float4 wv = *(const float4*)&W[(size_t)k * ws + bn + c4];
        Bs[(c4 + 0) * BS_STRIDE + k] = f2bf(wv.x);
        Bs[(c4 + 1) * BS_STRIDE + k] = f2bf(wv.y);
        Bs[(c4 + 2) * BS_STRIDE + k] = f2bf(wv.z);
        Bs[(c4 + 3) * BS_STRIDE + k] = f2bf(wv.w);
    }
    __syncthreads();
}

// ================= K1: segmax+gcw, seg, Q/K/V GEMMs, Hv->vacc2, Tpre =========
// blocks [0,16) segmax+gcw; 16 seg; [17,785) Q/K/V; [785,913) Hv; [913,1169) Tpre
__global__ __launch_bounds__(256) void k1_kernel(
    const float* __restrict__ x,
    const float* __restrict__ Wq, const float* __restrict__ bq,
    const float* __restrict__ Wk, const float* __restrict__ bk,
    const float* __restrict__ Wv, const float* __restrict__ bv,
    const float* __restrict__ Wv1, const float* __restrict__ bv1,
    const float* __restrict__ Wv2, const float* __restrict__ Wc1,
    const float* __restrict__ bc1, const int* __restrict__ batch,
    unsigned short* __restrict__ Qb, unsigned short* __restrict__ Kb,
    unsigned short* __restrict__ Vt, float* __restrict__ vacc2,
    float* __restrict__ Tpre, float* __restrict__ gcw, int* __restrict__ seg) {
    __shared__ __align__(16) char smem[64 * BS_STRIDE * 2];  // 33792 B
    int id = blockIdx.x, tid = threadIdx.x;
    if (id < 16) {  // ---- segmax (4-way row split) + gcw dot for graph id ----
        int g = id;
        int s = seg_search(batch, g), e = seg_search(batch, g + 1);
        float* red = (float*)smem;          // [4][256]
        float* gl  = (float*)smem + 1024;   // [256]
        int c4 = (tid & 63) * 4, way = tid >> 6;
        float4 mx = {-INFINITY, -INFINITY, -INFINITY, -INFINITY};
        for (int i = s + way; i < e; i += 4) {
            float4 v = *(const float4*)&x[(size_t)i * DIM + c4];
            mx.x = fmaxf(mx.x, v.x); mx.y = fmaxf(mx.y, v.y);
            mx.z = fmaxf(mx.z, v.z); mx.w = fmaxf(mx.w, v.w);
        }
        *(float4*)&red[way * 256 + c4] = mx;
        __syncthreads();
        if (way == 0) {
#pragma unroll
            for (int j = 0; j < 4; ++j) {
                float mm = fmaxf(fmaxf(red[c4 + j], red[256 + c4 + j]),
                                 fmaxf(red[512 + c4 + j], red[768 + c4 + j]));
                gl[c4 + j] = bf2f(f2bf(mm));  // bf16-rounded (consistent precision)
            }
        }
        __syncthreads();
        float a0 = 0.f, a1 = 0.f, a2 = 0.f, a3 = 0.f;
        for (int k = 0; k < 256; k += 4) {
            a0 += gl[k + 0] * Wc1[(size_t)(256 + k + 0) * 256 + tid];
            a1 += gl[k + 1] * Wc1[(size_t)(256 + k + 1) * 256 + tid];
            a2 += gl[k + 2] * Wc1[(size_t)(256 + k + 2) * 256 + tid];
            a3 += gl[k + 3] * Wc1[(size_t)(256 + k + 3) * 256 + tid];
        }
        gcw[g * 256 + tid] = (a0 + a1) + (a2 + a3);
        return;
    }
    if (id == 16) {
        if (tid <= NG) seg[tid] = seg_search(batch, tid);
        return;
    }
    int u = id - 17;
    unsigned short* Bs = (unsigned short*)smem;
    int w = tid >> 6, lane = tid & 63, m = lane & 15, quad = lane >> 4;
    if (u < 768) {  // ---- Q/K/V ----
        int z = u >> 8, r = u & 255, bx = r & 63, by = r >> 6;
        const float* W = (z == 0) ? Wq : (z == 1) ? Wk : Wv;
        const float* bias = (z == 0) ? bq : (z == 1) ? bk : bv;
        ldsB(W, 256, by * 64, Bs);
        int rowA = bx * 64 + 16 * w + m;
        short8 a[8];
#pragma unroll
        for (int ks = 0; ks < 8; ++ks) a[ks] = afrag_f32(x, rowA, ks * 32 + quad * 8);
        int node0 = bx * 64 + 16 * w + quad * 4;
#pragma unroll
        for (int nt = 0; nt < 4; ++nt) {
            f32x4 acc = {0.f, 0.f, 0.f, 0.f};
#pragma unroll
            for (int ks = 0; ks < 8; ++ks) {
                short8 b = *(const short8*)&Bs[(nt * 16 + m) * BS_STRIDE + ks * 32 + quad * 8];
                acc = __builtin_amdgcn_mfma_f32_16x16x32_bf16(a[ks], b, acc, 0, 0, 0);
            }
            int col = by * 64 + nt * 16 + m;
            float bb = bias[col];
            if (z == 0) {  // Q pre-scaled by 1/sqrt(64)
#pragma unroll
                for (int r2 = 0; r2 < 4; ++r2)
                    Qb[(size_t)(node0 + r2) * 256 + col] = f2bf((acc[r2] + bb) * 0.125f);
            } else if (z == 1) {
#pragma unroll
                for (int r2 = 0; r2 < 4; ++r2)
                    Kb[(size_t)(node0 + r2) * 256 + col] = f2bf(acc[r2] + bb);
            } else {
                short4_t pk = {(short)f2bf(acc[0] + bb), (short)f2bf(acc[1] + bb),
                               (short)f2bf(acc[2] + bb), (short)f2bf(acc[3] + bb)};
                *(short4_t*)&Vt[(size_t)col * RSLACK + node0] = pk;
            }
        }
    } else if (u < 896) {  // ---- Hv = relu(x@Wv1+bv1)·Wv2 -> vacc2 partial ----
        int r = u - 768, bx = r & 63, by = r >> 6;  // by in {0,1}
        ldsB(Wv1, 128, by * 64, Bs);
        int rowA = bx * 64 + 16 * w + m;
        short8 a[8];
#pragma unroll
        for (int ks = 0; ks < 8; ++ks) a[ks] = afrag_f32(x, rowA, ks * 32 + quad * 8);
        int node0 = bx * 64 + 16 * w + quad * 4;
        float psum[4] = {0.f, 0.f, 0.f, 0.f};
#pragma unroll
        for (int nt = 0; nt < 4; ++nt) {
            f32x4 acc = {0.f, 0.f, 0.f, 0.f};
#pragma unroll
            for (int ks = 0; ks < 8; ++ks) {
                short8 b = *(const short8*)&Bs[(nt * 16 + m) * BS_STRIDE + ks * 32 + quad * 8];
                acc = __builtin_amdgcn_mfma_f32_16x16x32_bf16(a[ks], b, acc, 0, 0, 0);
            }
            int col = by * 64 + nt * 16 + m;
            float bb = bv1[col], wv = Wv2[col];
#pragma unroll
            for (int r2 = 0; r2 < 4; ++r2) psum[r2] += fmaxf(acc[r2] + bb, 0.f) * wv;
        }
#pragma unroll
        for (int r2 = 0; r2 < 4; ++r2) {
#pragma unroll
            for (int mm = 1; mm < 16; mm <<= 1) psum[r2] += __shfl_xor(psum[r2], mm);
            if (m == 0) vacc2[(size_t)(node0 + r2) * 2 + by] = psum[r2];
        }
    } else {  // ---- Tpre = x@Wc1_top + bc1 (f32) ----
        int r = u - 896, bx = r & 63, by = r >> 6;  // by in [0,4)
        ldsB(Wc1, 256, by * 64, Bs);
        int rowA = bx * 64 + 16 * w + m;
        short8 a[8];
#pragma unroll
        for (int ks = 0; ks < 8; ++ks) a[ks] = afrag_f32(x, rowA, ks * 32 + quad * 8);
        int node0 = bx * 64 + 16 * w + quad * 4;
#pragma unroll
        for (int nt = 0; nt < 4; ++nt) {
            f32x4 acc = {0.f, 0.f, 0.f, 0.f};
#pragma unroll
            for (int ks = 0; ks < 8; ++ks) {
                short8 b = *(const short8*)&Bs[(nt * 16 + m) * BS_STRIDE + ks * 32 + quad * 8];
                acc = __builtin_amdgcn_mfma_f32_16x16x32_bf16(a[ks], b, acc, 0, 0, 0);
            }
            int col = by * 64 + nt * 16 + m;
            float bb = bc1[col];
#pragma unroll
            for (int r2 = 0; r2 < 4; ++r2)
                Tpre[(size_t)(node0 + r2) * 256 + col] = acc[r2] + bb;
        }
    }
}

// ================= K2: cacc (256) + full-accumulate attention (384) ==========
__global__ __launch_bounds__(256) void k2_kernel(
    const float* __restrict__ Tpre, const float* __restrict__ gcw,
    const float* __restrict__ Wc2, const int* __restrict__ batch,
    const unsigned short* __restrict__ Qb, const unsigned short* __restrict__ Kb,
    const unsigned short* __restrict__ Vt, const int* __restrict__ seg,
    unsigned short* __restrict__ Ofin, float* __restrict__ Lfin,
    float* __restrict__ cacc) {
    __shared__ __align__(16) unsigned short Ps[4 * 16 * PS_STRIDE];
    int tid = threadIdx.x;
    if (blockIdx.x < 256) {  // ---- cacc: 16 nodes/block ----
        int nl = tid >> 4, cs = (tid & 15) * 16;
        int node = blockIdx.x * 16 + nl;
        int g = batch[node];
        float sum = 0.f;
#pragma unroll
        for (int j = 0; j < 16; ++j) {
            int c = cs + j;
            sum += ftanh(Tpre[(size_t)node * 256 + c] + gcw[g * 256 + c]) * Wc2[c];
        }
#pragma unroll
        for (int mm = 1; mm < 16; mm <<= 1) sum += __shfl_xor(sum, mm);
        if ((tid & 15) == 0) cacc[node] = sum;
        return;
    }
    // ---- attention: block=(g,qt16), wave=head; accumulate over all key chunks
    int b = blockIdx.x - 256;
    int g = b / QT_MAX, qt = b - g * QT_MAX;
    int w = tid >> 6, lane = tid & 63, m = lane & 15, quad = lane >> 4;
    int h = w;
    int s = seg[g], e = seg[g + 1];
    int q0 = s + qt * 16;
    if (q0 >= e) return;

    short8 qa0 = *(const short8*)&Qb[(size_t)(q0 + m) * 256 + h * 64 + quad * 8];
    short8 qa1 = *(const short8*)&Qb[(size_t)(q0 + m) * 256 + h * 64 + 32 + quad * 8];
    short8 ones = {16256, 16256, 16256, 16256, 16256, 16256, 16256, 16256};  // bf16 1.0
    f32x4 O[4];
    f32x4 Lacc = {0.f, 0.f, 0.f, 0.f};
#pragma unroll
    for (int nt = 0; nt < 4; ++nt) O[nt] = (f32x4){0.f, 0.f, 0.f, 0.f};
    int wbase = w * 16 * PS_STRIDE;

    for (int k0 = s; k0 < e; k0 += 64) {
        f32x4 S[4];
#pragma unroll
        for (int nt = 0; nt < 4; ++nt) {
            int key = k0 + nt * 16 + m;
            short8 kb0 = *(const short8*)&Kb[(size_t)key * 256 + h * 64 + quad * 8];
            short8 kb1 = *(const short8*)&Kb[(size_t)key * 256 + h * 64 + 32 + quad * 8];
            f32x4 sa = {0.f, 0.f, 0.f, 0.f};
            sa = __builtin_amdgcn_mfma_f32_16x16x32_bf16(qa0, kb0, sa, 0, 0, 0);
            sa = __builtin_amdgcn_mfma_f32_16x16x32_bf16(qa1, kb1, sa, 0, 0, 0);
            S[nt] = sa;
        }
        __builtin_amdgcn_wave_barrier();  // don't sink stores above prior reads
#pragma unroll
        for (int nt = 0; nt < 4; ++nt) {
            bool valid = (k0 + nt * 16 + m) < e;
#pragma unroll
            for (int r3 = 0; r3 < 4; ++r3) {
                float p = valid ? __expf(S[nt][r3]) : 0.f;  // Q pre-scaled; S bounded
                Ps[wbase + (quad * 4 + r3) * PS_STRIDE + nt * 16 + m] = f2bf(p);
            }
        }
        __builtin_amdgcn_wave_barrier();  // LDS write->read order (in-order DS pipe)
        short8 pa0 = *(const short8*)&Ps[wbase + m * PS_STRIDE + quad * 8];
        short8 pa1 = *(const short8*)&Ps[wbase + m * PS_STRIDE + 32 + quad * 8];
        Lacc = __builtin_amdgcn_mfma_f32_16x16x32_bf16(pa0, ones, Lacc, 0, 0, 0);
        Lacc = __builtin_amdgcn_mfma_f32_16x16x32_bf16(pa1, ones, Lacc, 0, 0, 0);
#pragma unroll
        for (int nt = 0; nt < 4; ++nt) {
            const unsigned short* vrow = &Vt[(size_t)(h * 64 + nt * 16 + m) * RSLACK + k0];
            short8 vb0 = *(const short8*)&vrow[quad * 8];
            short8 vb1 = *(const short8*)&vrow[32 + quad * 8];
            O[nt] = __builtin_amdgcn_mfma_f32_16x16x32_bf16(pa0, vb0, O[nt], 0, 0, 0);
            O[nt] = __builtin_amdgcn_mfma_f32_16x16x32_bf16(pa1, vb1, O[nt], 0, 0, 0);
        }
    }
#pragma unroll
    for (int r3 = 0; r3 < 4; ++r3) {
        int q = q0 + quad * 4 + r3;
        if (q < e) {
            if (m == 0) Lfin[(size_t)q * 4 + h] = Lacc[r3];
#pragma unroll
            for (int nt = 0; nt < 4; ++nt)
                Ofin[(size_t)q * 256 + h * 64 + nt * 16 + m] = f2bf(O[nt][r3]);
        }
    }
}

// ================= K3: w + graph softmax + combine + residual + LN ===========
// 512 blocks x 8 nodes; per-graph softmax stats computed once per block
__global__ __launch_bounds__(256) void k3_kernel(
    const unsigned short* __restrict__ Ofin, const float* __restrict__ Lfin,
    const float* __restrict__ x, const float* __restrict__ vacc2,
    const float* __restrict__ cacc, const float* __restrict__ bv2,
    const float* __restrict__ bc2, const float* __restrict__ gamma,
    const float* __restrict__ beta, const int* __restrict__ batch,
    const int* __restrict__ seg, float* __restrict__ out,
    float* __restrict__ att_out) {
    __shared__ float wsc[776];
    __shared__ float gm[8], gsum[8];
    __shared__ float r1[4], r2[4];
    int tid = threadIdx.x;
    int n0 = blockIdx.x * 8;
    int gf = batch[n0], gl = batch[n0 + 7];
    int s0 = seg[gf], e1 = seg[gl + 1];
    float vb = bv2[0], cb = bc2[0];
    for (int j = s0 + tid; j < e1; j += 256) {
        float2 vv = *(const float2*)&vacc2[(size_t)j * 2];
        wsc[j - s0] = TEMP * (0.6f * fsigmoid(vv.x + vv.y + vb) +
                              0.3f * fsigmoid(cacc[j] + cb) + 0.1f / 4096.f);
    }
    __syncthreads();
    for (int g = gf; g <= gl; ++g) {
        int gs_ = seg[g], ge = seg[g + 1];
        float mx = -1e30f;
        for (int j = gs_ + tid; j < ge; j += 256) mx = fmaxf(mx, wsc[j - s0]);
#pragma unroll
        for (int k2 = 32; k2; k2 >>= 1) mx = fmaxf(mx, __shfl_xor(mx, k2));
        if ((tid & 63) == 0) r1[tid >> 6] = mx;
        __syncthreads();
        mx = fmaxf(fmaxf(r1[0], r1[1]), fmaxf(r1[2], r1[3]));
        float sm = 0.f;
        for (int j = gs_ + tid; j < ge; j += 256) sm += __expf(wsc[j - s0] - mx);
#pragma unroll
        for (int k2 = 32; k2; k2 >>= 1) sm += __shfl_xor(sm, k2);
        __syncthreads();
        if ((tid & 63) == 0) r2[tid >> 6] = sm;
        __syncthreads();
        if (tid == 0) {
            gm[g - gf] = mx;
            gsum[g - gf] = r2[0] + r2[1] + r2[2] + r2[3];
        }
        __syncthreads();
    }
    int h = tid >> 6;
    for (int i = 0; i < 8; ++i) {
        int n = n0 + i;
        int g = batch[n];
        float att_n = __expf(wsc[n - s0] - gm[g - gf]) / gsum[g - gf];
        if (tid == 0) att_out[n] = att_n;
        float L = Lfin[(size_t)n * 4 + h];
        float O = bf2f(Ofin[(size_t)n * 256 + tid]);
        float o = (O / L) * att_n + x[(size_t)n * 256 + tid];
        float s1 = o, s2 = o * o;
#pragma unroll
        for (int k2 = 32; k2; k2 >>= 1) {
            s1 += __shfl_xor(s1, k2);
            s2 += __shfl_xor(s2, k2);
        }
        __syncthreads();  // protect r1/r2 reuse across iterations
        if ((tid & 63) == 0) { r1[tid >> 6] = s1; r2[tid >> 6] = s2; }
        __syncthreads();
        float mu = (r1[0] + r1[1] + r1[2] + r1[3]) * (1.f / 256.f);
        float ms = (r2[0] + r2[1] + r2[2] + r2[3]) * (1.f / 256.f);
        float rs = rsqrtf(ms - mu * mu + LN_EPS);
        out[(size_t)n * 256 + tid] = (o - mu) * rs * gamma[tid] + beta[tid];
    }
}

extern "C" void kernel_launch(void* const* d_in, const int* in_sizes, int n_in,
                              void* d_out, int out_size, void* d_ws, size_t ws_size,
                              hipStream_t stream) {
    const float* x     = (const float*)d_in[0];
    const float* Wq    = (const float*)d_in[1];
    const float* bq    = (const float*)d_in[2];
    const float* Wk    = (const float*)d_in[3];
    const float* bk    = (const float*)d_in[4];
    const float* Wv    = (const float*)d_in[5];
    const float* bv    = (const float*)d_in[6];
    const float* Wv1   = (const float*)d_in[7];
    const float* bv1   = (const float*)d_in[8];
    const float* Wv2   = (const float*)d_in[9];
    const float* bv2   = (const float*)d_in[10];
    const float* Wc1   = (const float*)d_in[11];
    const float* bc1   = (const float*)d_in[12];
    const float* Wc2   = (const float*)d_in[13];
    const float* bc2   = (const float*)d_in[14];
    const float* gamma = (const float*)d_in[15];
    const float* beta  = (const float*)d_in[16];
    const int*   batch = (const int*)d_in[17];

    float* out = (float*)d_out;        // [N, D]
    float* att = out + N_NODES * DIM;  // [N]

    // f32 region (all written before read; no zeroing needed)
    float* vacc2 = (float*)d_ws;                        // 4096*2
    float* cacc  = vacc2 + N_NODES * 2;                 // 4096
    float* gcw   = cacc + N_NODES;                      // 16*256
    float* Lfin  = gcw + NG * DIM;                      // 4096*4
    float* Tpre  = Lfin + N_NODES * 4;                  // 4096*256
    int*   seg   = (int*)(Tpre + N_NODES * DIM);        // 32 ints
    // bf16 region
    unsigned short* Qb   = (unsigned short*)(seg + 32); // 4160*256
    unsigned short* Kb   = Qb + RSLACK * DIM;           // 4160*256
    unsigned short* Vt   = Kb + RSLACK * DIM;           // 256*4160
    unsigned short* Ofin = Vt + DIM * RSLACK;           // 4096*256

    k1_kernel<<<1169, 256, 0, stream>>>(x, Wq, bq, Wk, bk, Wv, bv, Wv1, bv1, Wv2,
                                        Wc1, bc1, batch, Qb, Kb, Vt, vacc2, Tpre,
                                        gcw, seg);
    k2_kernel<<<256 + ATTN_BLOCKS, 256, 0, stream>>>(Tpre, gcw, Wc2, batch,
                                                     Qb, Kb, Vt, seg,
                                                     Ofin, Lfin, cacc);
    k3_kernel<<<N_NODES / 8, 256, 0, stream>>>(Ofin, Lfin, x, vacc2, cacc,
                                               bv2, bc2, gamma, beta, batch, seg,
                                               out, att);
}

// Round 10
// 166.406 us; speedup vs baseline: 1.0697x; 1.0697x over previous
//
#include <hip/hip_runtime.h>
#include <math.h>

#define N_NODES 4096
#define DIM 256
#define NH 4
#define NG 16
#define LN_EPS 1e-5f
#define TEMP 5.0f
#define RSLACK 4160     // 4096 + 64 rows of slack for attention tile-tail reads
#define PS_STRIDE 72    // bf16 elems; 144 B row stride, 2-way aliasing only (free)
#define BS_STRIDE 264   // bf16 elems; 528 B row stride -> 2-way-free b128 reads
#define QT_MAX 24       // 24*16 = 384 max rows/graph
#define KC3 3           // 3-way key split (128 keys per split, 2 inner chunks)
#define ATTN_BLOCKS (NG * QT_MAX * KC3)  // 1152: block = 4 waves of (g,qt,h,kc)

typedef __attribute__((ext_vector_type(8))) short short8;
typedef __attribute__((ext_vector_type(4))) short short4_t;
typedef __attribute__((ext_vector_type(4))) float f32x4;

__device__ __forceinline__ unsigned short f2bf(float f) {
    unsigned u = __builtin_bit_cast(unsigned, f);
    u += 0x7FFFu + ((u >> 16) & 1u);  // RNE
    return (unsigned short)(u >> 16);
}
__device__ __forceinline__ float bf2f(unsigned short u) {
    return __builtin_bit_cast(float, (unsigned)u << 16);
}
__device__ __forceinline__ float fsigmoid(float z) { return 1.f / (1.f + __expf(-z)); }
__device__ __forceinline__ float ftanh(float z) {
    float t = __expf(2.f * z);
    return (t - 1.f) / (t + 1.f);
}
__device__ __forceinline__ int seg_search(const int* __restrict__ batch, int g) {
    int lo = 0, hi = N_NODES;
    while (lo < hi) {
        int mid = (lo + hi) >> 1;
        if (batch[mid] < g) lo = mid + 1; else hi = mid;
    }
    return lo;
}

// A-fragment: 8 consecutive k of f32 x, cast bf16 in-register (same RNE values
// as a staged bf16 copy of x).
__device__ __forceinline__ short8 afrag_f32(const float* __restrict__ x, int row, int k0) {
    float4 a = *(const float4*)&x[(size_t)row * 256 + k0];
    float4 b = *(const float4*)&x[(size_t)row * 256 + k0 + 4];
    short8 r = {(short)f2bf(a.x), (short)f2bf(a.y), (short)f2bf(a.z), (short)f2bf(a.w),
                (short)f2bf(b.x), (short)f2bf(b.y), (short)f2bf(b.z), (short)f2bf(b.w)};
    return r;
}

// Cooperative 64-col W-tile load + transpose + bf16 cast into LDS: Bs[c][k].
__device__ __forceinline__ void ldsB(const float* __restrict__ W, int ws, int bn,
                                     unsigned short* __restrict__ Bs) {
    int c4 = (threadIdx.x & 15) * 4;
    int r0 = threadIdx.x >> 4;
    for (int p = 0; p < 16; ++p) {
        int k = p * 16 + r0;
        float4 wv = *(const float4*)&W[(size_t)k * ws + bn + c4];
        Bs[(c4 + 0) * BS_STRIDE + k] = f2bf(wv.x);
        Bs[(c4 + 1) * BS_STRIDE + k] = f2bf(wv.y);
        Bs[(c4 + 2) * BS_STRIDE + k] = f2bf(wv.z);
        Bs[(c4 + 3) * BS_STRIDE + k] = f2bf(wv.w);
    }
    __syncthreads();
}

// ================= K1: segmax+gcw, seg, Q/K/V GEMMs, Hv->vacc2, Tpre =========
// blocks [0,16) segmax+gcw; 16 seg; [17,785) Q/K/V; [785,913) Hv; [913,1169) Tpre
__global__ __launch_bounds__(256) void k1_kernel(
    const float* __restrict__ x,
    const float* __restrict__ Wq, const float* __restrict__ bq,
    const float* __restrict__ Wk, const float* __restrict__ bk,
    const float* __restrict__ Wv, const float* __restrict__ bv,
    const float* __restrict__ Wv1, const float* __restrict__ bv1,
    const float* __restrict__ Wv2, const float* __restrict__ Wc1,
    const float* __restrict__ bc1, const int* __restrict__ batch,
    unsigned short* __restrict__ Qb, unsigned short* __restrict__ Kb,
    unsigned short* __restrict__ Vt, float* __restrict__ vacc2,
    float* __restrict__ Tpre, float* __restrict__ gcw, int* __restrict__ seg) {
    __shared__ __align__(16) char smem[64 * BS_STRIDE * 2];  // 33792 B
    int id = blockIdx.x, tid = threadIdx.x;
    if (id < 16) {  // ---- segmax (4-way row split) + gcw dot for graph id ----
        int g = id;
        int s = seg_search(batch, g), e = seg_search(batch, g + 1);
        float* red = (float*)smem;          // [4][256]
        float* gl  = (float*)smem + 1024;   // [256]
        int c4 = (tid & 63) * 4, way = tid >> 6;
        float4 mx = {-INFINITY, -INFINITY, -INFINITY, -INFINITY};
        for (int i = s + way; i < e; i += 4) {
            float4 v = *(const float4*)&x[(size_t)i * DIM + c4];
            mx.x = fmaxf(mx.x, v.x); mx.y = fmaxf(mx.y, v.y);
            mx.z = fmaxf(mx.z, v.z); mx.w = fmaxf(mx.w, v.w);
        }
        *(float4*)&red[way * 256 + c4] = mx;
        __syncthreads();
        if (way == 0) {
#pragma unroll
            for (int j = 0; j < 4; ++j) {
                float mm = fmaxf(fmaxf(red[c4 + j], red[256 + c4 + j]),
                                 fmaxf(red[512 + c4 + j], red[768 + c4 + j]));
                gl[c4 + j] = bf2f(f2bf(mm));  // bf16-rounded (consistent precision)
            }
        }
        __syncthreads();
        float a0 = 0.f, a1 = 0.f, a2 = 0.f, a3 = 0.f;
        for (int k = 0; k < 256; k += 4) {
            a0 += gl[k + 0] * Wc1[(size_t)(256 + k + 0) * 256 + tid];
            a1 += gl[k + 1] * Wc1[(size_t)(256 + k + 1) * 256 + tid];
            a2 += gl[k + 2] * Wc1[(size_t)(256 + k + 2) * 256 + tid];
            a3 += gl[k + 3] * Wc1[(size_t)(256 + k + 3) * 256 + tid];
        }
        gcw[g * 256 + tid] = (a0 + a1) + (a2 + a3);
        return;
    }
    if (id == 16) {
        if (tid <= NG) seg[tid] = seg_search(batch, tid);
        return;
    }
    int u = id - 17;
    unsigned short* Bs = (unsigned short*)smem;
    int w = tid >> 6, lane = tid & 63, m = lane & 15, quad = lane >> 4;
    if (u < 768) {  // ---- Q/K/V ----
        int z = u >> 8, r = u & 255, bx = r & 63, by = r >> 6;
        const float* W = (z == 0) ? Wq : (z == 1) ? Wk : Wv;
        const float* bias = (z == 0) ? bq : (z == 1) ? bk : bv;
        ldsB(W, 256, by * 64, Bs);
        int rowA = bx * 64 + 16 * w + m;
        short8 a[8];
#pragma unroll
        for (int ks = 0; ks < 8; ++ks) a[ks] = afrag_f32(x, rowA, ks * 32 + quad * 8);
        int node0 = bx * 64 + 16 * w + quad * 4;
#pragma unroll
        for (int nt = 0; nt < 4; ++nt) {
            f32x4 acc = {0.f, 0.f, 0.f, 0.f};
#pragma unroll
            for (int ks = 0; ks < 8; ++ks) {
                short8 b = *(const short8*)&Bs[(nt * 16 + m) * BS_STRIDE + ks * 32 + quad * 8];
                acc = __builtin_amdgcn_mfma_f32_16x16x32_bf16(a[ks], b, acc, 0, 0, 0);
            }
            int col = by * 64 + nt * 16 + m;
            float bb = bias[col];
            if (z == 0) {  // Q pre-scaled by 1/sqrt(64)
#pragma unroll
                for (int r2 = 0; r2 < 4; ++r2)
                    Qb[(size_t)(node0 + r2) * 256 + col] = f2bf((acc[r2] + bb) * 0.125f);
            } else if (z == 1) {
#pragma unroll
                for (int r2 = 0; r2 < 4; ++r2)
                    Kb[(size_t)(node0 + r2) * 256 + col] = f2bf(acc[r2] + bb);
            } else {
                short4_t pk = {(short)f2bf(acc[0] + bb), (short)f2bf(acc[1] + bb),
                               (short)f2bf(acc[2] + bb), (short)f2bf(acc[3] + bb)};
                *(short4_t*)&Vt[(size_t)col * RSLACK + node0] = pk;
            }
        }
    } else if (u < 896) {  // ---- Hv = relu(x@Wv1+bv1)·Wv2 -> vacc2 partial ----
        int r = u - 768, bx = r & 63, by = r >> 6;  // by in {0,1}
        ldsB(Wv1, 128, by * 64, Bs);
        int rowA = bx * 64 + 16 * w + m;
        short8 a[8];
#pragma unroll
        for (int ks = 0; ks < 8; ++ks) a[ks] = afrag_f32(x, rowA, ks * 32 + quad * 8);
        int node0 = bx * 64 + 16 * w + quad * 4;
        float psum[4] = {0.f, 0.f, 0.f, 0.f};
#pragma unroll
        for (int nt = 0; nt < 4; ++nt) {
            f32x4 acc = {0.f, 0.f, 0.f, 0.f};
#pragma unroll
            for (int ks = 0; ks < 8; ++ks) {
                short8 b = *(const short8*)&Bs[(nt * 16 + m) * BS_STRIDE + ks * 32 + quad * 8];
                acc = __builtin_amdgcn_mfma_f32_16x16x32_bf16(a[ks], b, acc, 0, 0, 0);
            }
            int col = by * 64 + nt * 16 + m;
            float bb = bv1[col], wv = Wv2[col];
#pragma unroll
            for (int r2 = 0; r2 < 4; ++r2) psum[r2] += fmaxf(acc[r2] + bb, 0.f) * wv;
        }
#pragma unroll
        for (int r2 = 0; r2 < 4; ++r2) {
#pragma unroll
            for (int mm = 1; mm < 16; mm <<= 1) psum[r2] += __shfl_xor(psum[r2], mm);
            if (m == 0) vacc2[(size_t)(node0 + r2) * 2 + by] = psum[r2];
        }
    } else {  // ---- Tpre = x@Wc1_top + bc1 (f32) ----
        int r = u - 896, bx = r & 63, by = r >> 6;  // by in [0,4)
        ldsB(Wc1, 256, by * 64, Bs);
        int rowA = bx * 64 + 16 * w + m;
        short8 a[8];
#pragma unroll
        for (int ks = 0; ks < 8; ++ks) a[ks] = afrag_f32(x, rowA, ks * 32 + quad * 8);
        int node0 = bx * 64 + 16 * w + quad * 4;
#pragma unroll
        for (int nt = 0; nt < 4; ++nt) {
            f32x4 acc = {0.f, 0.f, 0.f, 0.f};
#pragma unroll
            for (int ks = 0; ks < 8; ++ks) {
                short8 b = *(const short8*)&Bs[(nt * 16 + m) * BS_STRIDE + ks * 32 + quad * 8];
                acc = __builtin_amdgcn_mfma_f32_16x16x32_bf16(a[ks], b, acc, 0, 0, 0);
            }
            int col = by * 64 + nt * 16 + m;
            float bb = bc1[col];
#pragma unroll
            for (int r2 = 0; r2 < 4; ++r2)
                Tpre[(size_t)(node0 + r2) * 256 + col] = acc[r2] + bb;
        }
    }
}

// ================= K2: cacc (256) + 3-way key-split attention (1152) =========
__global__ __launch_bounds__(256) void k2_kernel(
    const float* __restrict__ Tpre, const float* __restrict__ gcw,
    const float* __restrict__ Wc2, const int* __restrict__ batch,
    const unsigned short* __restrict__ Qb, const unsigned short* __restrict__ Kb,
    const unsigned short* __restrict__ Vt, const int* __restrict__ seg,
    unsigned short* __restrict__ Opart, float* __restrict__ Lpart,
    float* __restrict__ cacc) {
    __shared__ __align__(16) unsigned short Ps[4 * 16 * PS_STRIDE];
    int tid = threadIdx.x;
    if (blockIdx.x < 256) {  // ---- cacc: 16 nodes/block ----
        int nl = tid >> 4, cs = (tid & 15) * 16;
        int node = blockIdx.x * 16 + nl;
        int g = batch[node];
        float sum = 0.f;
#pragma unroll
        for (int j = 0; j < 16; ++j) {
            int c = cs + j;
            sum += ftanh(Tpre[(size_t)node * 256 + c] + gcw[g * 256 + c]) * Wc2[c];
        }
#pragma unroll
        for (int mm = 1; mm < 16; mm <<= 1) sum += __shfl_xor(sum, mm);
        if ((tid & 15) == 0) cacc[node] = sum;
        return;
    }
    // ---- attention partial: wave = (g, qt, h, kc); <=2 chunks of 64 keys ----
    int w = tid >> 6, lane = tid & 63, m = lane & 15, quad = lane >> 4;
    int wid = (blockIdx.x - 256) * 4 + w;
    int g = wid / (KC3 * QT_MAX * NH);
    int r1 = wid - g * (KC3 * QT_MAX * NH);
    int kc = r1 / (QT_MAX * NH);
    int r2i = r1 - kc * (QT_MAX * NH);
    int qt = r2i >> 2, h = r2i & 3;
    int s = seg[g], e = seg[g + 1];
    int q0 = s + qt * 16;
    int kst = s + kc * 128;
    if (q0 >= e || kst >= e) return;
    int ken = min(e, kst + 128);

    short8 qa0 = *(const short8*)&Qb[(size_t)(q0 + m) * 256 + h * 64 + quad * 8];
    short8 qa1 = *(const short8*)&Qb[(size_t)(q0 + m) * 256 + h * 64 + 32 + quad * 8];
    short8 ones = {16256, 16256, 16256, 16256, 16256, 16256, 16256, 16256};  // bf16 1.0
    f32x4 O[4];
    f32x4 Lacc = {0.f, 0.f, 0.f, 0.f};
#pragma unroll
    for (int nt = 0; nt < 4; ++nt) O[nt] = (f32x4){0.f, 0.f, 0.f, 0.f};
    int wbase = w * 16 * PS_STRIDE;

    for (int k0 = kst; k0 < ken; k0 += 64) {
        f32x4 S[4];
#pragma unroll
        for (int nt = 0; nt < 4; ++nt) {
            int key = k0 + nt * 16 + m;
            short8 kb0 = *(const short8*)&Kb[(size_t)key * 256 + h * 64 + quad * 8];
            short8 kb1 = *(const short8*)&Kb[(size_t)key * 256 + h * 64 + 32 + quad * 8];
            f32x4 sa = {0.f, 0.f, 0.f, 0.f};
            sa = __builtin_amdgcn_mfma_f32_16x16x32_bf16(qa0, kb0, sa, 0, 0, 0);
            sa = __builtin_amdgcn_mfma_f32_16x16x32_bf16(qa1, kb1, sa, 0, 0, 0);
            S[nt] = sa;
        }
        __builtin_amdgcn_wave_barrier();  // don't sink LDS stores above prior reads
#pragma unroll
        for (int nt = 0; nt < 4; ++nt) {
            bool valid = (k0 + nt * 16 + m) < e;
#pragma unroll
            for (int r3 = 0; r3 < 4; ++r3) {
                float p = valid ? __expf(S[nt][r3]) : 0.f;  // Q pre-scaled; S bounded
                Ps[wbase + (quad * 4 + r3) * PS_STRIDE + nt * 16 + m] = f2bf(p);
            }
        }
        __builtin_amdgcn_wave_barrier();  // LDS write->read order (in-order DS pipe)
        short8 pa0 = *(const short8*)&Ps[wbase + m * PS_STRIDE + quad * 8];
        short8 pa1 = *(const short8*)&Ps[wbase + m * PS_STRIDE + 32 + quad * 8];
        Lacc = __builtin_amdgcn_mfma_f32_16x16x32_bf16(pa0, ones, Lacc, 0, 0, 0);
        Lacc = __builtin_amdgcn_mfma_f32_16x16x32_bf16(pa1, ones, Lacc, 0, 0, 0);
#pragma unroll
        for (int nt = 0; nt < 4; ++nt) {
            const unsigned short* vrow = &Vt[(size_t)(h * 64 + nt * 16 + m) * RSLACK + k0];
            short8 vb0 = *(const short8*)&vrow[quad * 8];
            short8 vb1 = *(const short8*)&vrow[32 + quad * 8];
            O[nt] = __builtin_amdgcn_mfma_f32_16x16x32_bf16(pa0, vb0, O[nt], 0, 0, 0);
            O[nt] = __builtin_amdgcn_mfma_f32_16x16x32_bf16(pa1, vb1, O[nt], 0, 0, 0);
        }
    }
#pragma unroll
    for (int r3 = 0; r3 < 4; ++r3) {
        int q = q0 + quad * 4 + r3;
        if (q < e) {
            if (m == 0) Lpart[((size_t)kc * N_NODES + q) * 4 + h] = Lacc[r3];
#pragma unroll
            for (int nt = 0; nt < 4; ++nt)
                Opart[((size_t)kc * N_NODES + q) * 256 + h * 64 + nt * 16 + m] =
                    f2bf(O[nt][r3]);
        }
    }
}

// ================= K3: w + graph softmax + combine + residual + LN ===========
// 512 blocks x 8 nodes; per-graph softmax stats computed once per block
__global__ __launch_bounds__(256) void k3_kernel(
    const unsigned short* __restrict__ Opart, const float* __restrict__ Lpart,
    const float* __restrict__ x, const float* __restrict__ vacc2,
    const float* __restrict__ cacc, const float* __restrict__ bv2,
    const float* __restrict__ bc2, const float* __restrict__ gamma,
    const float* __restrict__ beta, const int* __restrict__ batch,
    const int* __restrict__ seg, float* __restrict__ out,
    float* __restrict__ att_out) {
    __shared__ float wsc[776];
    __shared__ float gm[8], gsum[8];
    __shared__ float r1[4], r2[4];
    int tid = threadIdx.x;
    int n0 = blockIdx.x * 8;
    int gf = batch[n0], gl = batch[n0 + 7];
    int s0 = seg[gf], e1 = seg[gl + 1];
    float vb = bv2[0], cb = bc2[0];
    for (int j = s0 + tid; j < e1; j += 256) {
        float2 vv = *(const float2*)&vacc2[(size_t)j * 2];
        wsc[j - s0] = TEMP * (0.6f * fsigmoid(vv.x + vv.y + vb) +
                              0.3f * fsigmoid(cacc[j] + cb) + 0.1f / 4096.f);
    }
    __syncthreads();
    for (int g = gf; g <= gl; ++g) {
        int gs_ = seg[g], ge = seg[g + 1];
        float mx = -1e30f;
        for (int j = gs_ + tid; j < ge; j += 256) mx = fmaxf(mx, wsc[j - s0]);
#pragma unroll
        for (int k2 = 32; k2; k2 >>= 1) mx = fmaxf(mx, __shfl_xor(mx, k2));
        if ((tid & 63) == 0) r1[tid >> 6] = mx;
        __syncthreads();
        mx = fmaxf(fmaxf(r1[0], r1[1]), fmaxf(r1[2], r1[3]));
        float sm = 0.f;
        for (int j = gs_ + tid; j < ge; j += 256) sm += __expf(wsc[j - s0] - mx);
#pragma unroll
        for (int k2 = 32; k2; k2 >>= 1) sm += __shfl_xor(sm, k2);
        __syncthreads();
        if ((tid & 63) == 0) r2[tid >> 6] = sm;
        __syncthreads();
        if (tid == 0) {
            gm[g - gf] = mx;
            gsum[g - gf] = r2[0] + r2[1] + r2[2] + r2[3];
        }
        __syncthreads();
    }
    int h = tid >> 6;
    for (int i = 0; i < 8; ++i) {
        int n = n0 + i;
        int g = batch[n];
        int s = seg[g], e = seg[g + 1];
        float att_n = __expf(wsc[n - s0] - gm[g - gf]) / gsum[g - gf];
        if (tid == 0) att_out[n] = att_n;
        float L = 0.f, O = 0.f;
#pragma unroll
        for (int c = 0; c < KC3; ++c) {
            bool valid = (s + c * 128) < e;
            float lv = Lpart[((size_t)c * N_NODES + n) * 4 + h];
            float ov = bf2f(Opart[((size_t)c * N_NODES + n) * 256 + tid]);
            if (valid) { L += lv; O += ov; }
        }
        float o = (O / L) * att_n + x[(size_t)n * 256 + tid];
        float s1 = o, s2 = o * o;
#pragma unroll
        for (int k2 = 32; k2; k2 >>= 1) {
            s1 += __shfl_xor(s1, k2);
            s2 += __shfl_xor(s2, k2);
        }
        __syncthreads();  // protect r1/r2 reuse across iterations
        if ((tid & 63) == 0) { r1[tid >> 6] = s1; r2[tid >> 6] = s2; }
        __syncthreads();
        float mu = (r1[0] + r1[1] + r1[2] + r1[3]) * (1.f / 256.f);
        float ms = (r2[0] + r2[1] + r2[2] + r2[3]) * (1.f / 256.f);
        float rs = rsqrtf(ms - mu * mu + LN_EPS);
        out[(size_t)n * 256 + tid] = (o - mu) * rs * gamma[tid] + beta[tid];
    }
}

extern "C" void kernel_launch(void* const* d_in, const int* in_sizes, int n_in,
                              void* d_out, int out_size, void* d_ws, size_t ws_size,
                              hipStream_t stream) {
    const float* x     = (const float*)d_in[0];
    const float* Wq    = (const float*)d_in[1];
    const float* bq    = (const float*)d_in[2];
    const float* Wk    = (const float*)d_in[3];
    const float* bk    = (const float*)d_in[4];
    const float* Wv    = (const float*)d_in[5];
    const float* bv    = (const float*)d_in[6];
    const float* Wv1   = (const float*)d_in[7];
    const float* bv1   = (const float*)d_in[8];
    const float* Wv2   = (const float*)d_in[9];
    const float* bv2   = (const float*)d_in[10];
    const float* Wc1   = (const float*)d_in[11];
    const float* bc1   = (const float*)d_in[12];
    const float* Wc2   = (const float*)d_in[13];
    const float* bc2   = (const float*)d_in[14];
    const float* gamma = (const float*)d_in[15];
    const float* beta  = (const float*)d_in[16];
    const int*   batch = (const int*)d_in[17];

    float* out = (float*)d_out;        // [N, D]
    float* att = out + N_NODES * DIM;  // [N]

    // f32 region (all written before read; no zeroing needed)
    float* vacc2 = (float*)d_ws;                        // 4096*2
    float* cacc  = vacc2 + N_NODES * 2;                 // 4096
    float* gcw   = cacc + N_NODES;                      // 16*256
    float* Lpart = gcw + NG * DIM;                      // 3*4096*4
    float* Tpre  = Lpart + KC3 * N_NODES * 4;           // 4096*256
    int*   seg   = (int*)(Tpre + N_NODES * DIM);        // 32 ints
    // bf16 region
    unsigned short* Qb    = (unsigned short*)(seg + 32);  // 4160*256
    unsigned short* Kb    = Qb + RSLACK * DIM;            // 4160*256
    unsigned short* Vt    = Kb + RSLACK * DIM;            // 256*4160
    unsigned short* Opart = Vt + DIM * RSLACK;            // 3*4096*256

    k1_kernel<<<1169, 256, 0, stream>>>(x, Wq, bq, Wk, bk, Wv, bv, Wv1, bv1, Wv2,
                                        Wc1, bc1, batch, Qb, Kb, Vt, vacc2, Tpre,
                                        gcw, seg);
    k2_kernel<<<256 + ATTN_BLOCKS, 256, 0, stream>>>(Tpre, gcw, Wc2, batch,
                                                     Qb, Kb, Vt, seg,
                                                     Opart, Lpart, cacc);
    k3_kernel<<<N_NODES / 8, 256, 0, stream>>>(Opart, Lpart, x, vacc2, cacc,
                                               bv2, bc2, gamma, beta, batch, seg,
                                               out, att);
}